// Round 7
// baseline (547.306 us; speedup 1.0000x reference)
//
#include <hip/hip_runtime.h>
#include <math.h>

typedef unsigned short u16;
typedef __attribute__((ext_vector_type(8))) short short8;
typedef __attribute__((ext_vector_type(4))) float f32x4;
typedef __attribute__((ext_vector_type(4))) unsigned short us4;

// Inputs f32, output f32 (proven rounds 4-5).

static __device__ __forceinline__ float bf2f(u16 u) {
    unsigned v = ((unsigned)u) << 16;
    return __builtin_bit_cast(float, v);
}
static __device__ __forceinline__ u16 f2bf(float f) {
    unsigned x = __builtin_bit_cast(unsigned, f);
    unsigned r = x + 0x7fffu + ((x >> 16) & 1u);
    return (u16)(r >> 16);
}
static __device__ __forceinline__ void splitbf(float f, u16 &hi, u16 &lo) {
    hi = f2bf(f);
    lo = f2bf(f - bf2f(hi));
}
// value-returning variant: low 16 = hi part, high 16 = lo part
static __device__ __forceinline__ unsigned splitbf2(float f) {
    u16 hi = f2bf(f);
    u16 lo = f2bf(f - bf2f(hi));
    return (unsigned)hi | ((unsigned)lo << 16);
}

// ---------- weight transpose+split: WTh/WTl[w][n][k] = split(W[w][k][n]) ----------
__global__ __launch_bounds__(256) void transpose_w(
    const float* __restrict__ Wq, const float* __restrict__ Wk, const float* __restrict__ Wv,
    const float* __restrict__ Wg, const float* __restrict__ Wo, const float* __restrict__ W1,
    const float* __restrict__ W2, u16* __restrict__ WTh, u16* __restrict__ WTl)
{
    __shared__ float tile[64][65];
    const float* Ws[7] = {Wq, Wk, Wv, Wg, Wo, W1, W2};
    int w = blockIdx.z;
    int k0 = blockIdx.x * 64, n0 = blockIdx.y * 64;
    const float* W = Ws[w];
    int t = threadIdx.x;
    for (int c = t; c < 4096; c += 256) {
        int row = c >> 6, col = c & 63;
        tile[row][col] = W[(size_t)(k0 + row) * 512 + n0 + col];
    }
    __syncthreads();
    for (int c = t; c < 4096; c += 256) {
        int row = c >> 6, col = c & 63;
        u16 hi, lo;
        splitbf(tile[col][row], hi, lo);
        size_t o = (size_t)w * 262144 + (size_t)(n0 + row) * 512 + k0 + col;
        WTh[o] = hi;
        WTl[o] = lo;
    }
}

// ---------- LayerNorm; writes f32 and/or pre-split bf16 [row][hi(512)|lo(512)] ----------
__global__ __launch_bounds__(256) void ln_kernel(
    const float* __restrict__ xin,
    const int* __restrict__ ids, const float* __restrict__ emb, const float* __restrict__ pos,
    const float* __restrict__ gam, const float* __restrict__ bet,
    float* __restrict__ outf, u16* __restrict__ outsplit, int mode, float* __restrict__ zero8)
{
    __shared__ float red[8];
    int row = blockIdx.x, t = threadIdx.x;
    int wid = t >> 6, lane = t & 63;
    float v0, v1;
    if (mode == 1) {
        int id = ids[2 * 8192 + row];
        const float* e = emb + (size_t)(2 * 1024 + id) * 512;
        const float* p = pos + (size_t)(2 * 1024 + (row & 1023)) * 512;
        v0 = e[t] + p[t];
        v1 = e[t + 256] + p[t + 256];
    } else {
        v0 = xin[(size_t)row * 512 + t];
        v1 = xin[(size_t)row * 512 + t + 256];
    }
    float s1 = v0 + v1, s2 = v0 * v0 + v1 * v1;
#pragma unroll
    for (int o = 32; o >= 1; o >>= 1) {
        s1 += __shfl_xor(s1, o, 64);
        s2 += __shfl_xor(s2, o, 64);
    }
    if (lane == 0) { red[wid] = s1; red[4 + wid] = s2; }
    __syncthreads();
    float S1 = red[0] + red[1] + red[2] + red[3];
    float S2 = red[4] + red[5] + red[6] + red[7];
    float mu = S1 * (1.f / 512.f);
    float var = fmaxf(S2 * (1.f / 512.f) - mu * mu, 0.f);
    float rs = 1.f / sqrtf(var + 1e-5f);
    float y0 = (v0 - mu) * rs * gam[t] + bet[t];
    float y1 = (v1 - mu) * rs * gam[t + 256] + bet[t + 256];
    if (outf) {
        outf[(size_t)row * 512 + t] = y0;
        outf[(size_t)row * 512 + t + 256] = y1;
    }
    if (outsplit) {
        u16 hi, lo;
        splitbf(y0, hi, lo);
        outsplit[(size_t)row * 1024 + t] = hi;
        outsplit[(size_t)row * 1024 + 512 + t] = lo;
        splitbf(y1, hi, lo);
        outsplit[(size_t)row * 1024 + t + 256] = hi;
        outsplit[(size_t)row * 1024 + 512 + t + 256] = lo;
    }
    if (zero8 && row == 0 && t < 8) zero8[t] = 0.f;
}

// ---------- GEMM: A2 pre-split [m][hi|lo] x WT[n][k]; 3-term split MFMA ----------
// concat-K: ki<16 => A-hi chunk (Ah*Bh and Ah*Bl terms); ki>=16 => A-lo (Al*Bh).
// mode 0: outf=C ; 1: outf=C+res ; 2: outsplit=split(relu(C+bias)) ; 3: outf=C+bias+res
__global__ __launch_bounds__(256) void gemm_split(
    const u16* __restrict__ A2, const u16* __restrict__ Bhg, const u16* __restrict__ Blg,
    float* __restrict__ outf, u16* __restrict__ outsplit,
    const float* __restrict__ res, const float* __restrict__ bias, int mode, int ostride)
{
    __shared__ u16 As[128 * 40];
    __shared__ u16 Bh[128 * 40];
    __shared__ u16 Bl[128 * 40];
    int t = threadIdx.x;
    int wid = t >> 6, lane = t & 63, quad = lane >> 4, l15 = lane & 15;
    int wm = wid >> 1, wn = wid & 1;
    int m0 = blockIdx.y * 128, n0 = blockIdx.x * 128;

    f32x4 acc[4][4];
#pragma unroll
    for (int a = 0; a < 4; ++a)
#pragma unroll
        for (int b = 0; b < 4; ++b) acc[a][b] = (f32x4){0.f, 0.f, 0.f, 0.f};

    for (int ki = 0; ki < 32; ++ki) {
        int k0 = ki * 32, kb = k0 & 511;
        bool hiA = ki < 16;
        __syncthreads();
#pragma unroll
        for (int i = 0; i < 2; ++i) {
            int c = t + i * 256;
            int row = c >> 2, part = c & 3;
            *(short8*)&As[row * 40 + part * 8] =
                *(const short8*)&A2[(size_t)(m0 + row) * 1024 + k0 + part * 8];
            *(short8*)&Bh[row * 40 + part * 8] =
                *(const short8*)&Bhg[(size_t)(n0 + row) * 512 + kb + part * 8];
            if (hiA)
                *(short8*)&Bl[row * 40 + part * 8] =
                    *(const short8*)&Blg[(size_t)(n0 + row) * 512 + kb + part * 8];
        }
        __syncthreads();
        short8 af[4], bh[4];
#pragma unroll
        for (int tm = 0; tm < 4; ++tm)
            af[tm] = *(const short8*)&As[(wm * 64 + tm * 16 + l15) * 40 + quad * 8];
#pragma unroll
        for (int tn = 0; tn < 4; ++tn)
            bh[tn] = *(const short8*)&Bh[(wn * 64 + tn * 16 + l15) * 40 + quad * 8];
#pragma unroll
        for (int tm = 0; tm < 4; ++tm)
#pragma unroll
            for (int tn = 0; tn < 4; ++tn)
                acc[tm][tn] = __builtin_amdgcn_mfma_f32_16x16x32_bf16(af[tm], bh[tn], acc[tm][tn], 0, 0, 0);
        if (hiA) {
            short8 bl[4];
#pragma unroll
            for (int tn = 0; tn < 4; ++tn)
                bl[tn] = *(const short8*)&Bl[(wn * 64 + tn * 16 + l15) * 40 + quad * 8];
#pragma unroll
            for (int tm = 0; tm < 4; ++tm)
#pragma unroll
                for (int tn = 0; tn < 4; ++tn)
                    acc[tm][tn] = __builtin_amdgcn_mfma_f32_16x16x32_bf16(af[tm], bl[tn], acc[tm][tn], 0, 0, 0);
        }
    }

#pragma unroll
    for (int tm = 0; tm < 4; ++tm) {
#pragma unroll
        for (int tn = 0; tn < 4; ++tn) {
            int n = n0 + wn * 64 + tn * 16 + l15;
            int mbase = m0 + wm * 64 + tm * 16 + quad * 4;
#pragma unroll
            for (int r = 0; r < 4; ++r) {
                int m = mbase + r;
                float v = acc[tm][tn][r];
                if (mode == 1) v += res[(size_t)m * 512 + n];
                else if (mode == 2) v = fmaxf(v + bias[n], 0.f);
                else if (mode == 3) v += bias[n] + res[(size_t)m * 512 + n];
                if (mode == 2) {
                    u16 hi, lo;
                    splitbf(v, hi, lo);
                    outsplit[(size_t)m * 1024 + n] = hi;
                    outsplit[(size_t)m * 1024 + 512 + n] = lo;
                } else {
                    outf[(size_t)m * ostride + n] = v;
                }
            }
        }
    }
}

// ---------- fused retention: QK^T -> decay -> PV -> groupnorm -> swish gate -> split Z ----------
// V^T LDS rotation-swizzled: (d, m) at d*72 + (((m>>3)+d)&7)*8 + (m&7)
// P tile per-wave f32 stride 68 (writes 2-way, reads balanced); no barrier on P round-trip.
__global__ __launch_bounds__(256) void retention_mfma(
    const float* __restrict__ QKVG, u16* __restrict__ Zs)
{
    __shared__ u16 kh[64 * 72], kl[64 * 72];
    __shared__ u16 vth[64 * 72], vtl[64 * 72];
    __shared__ float pf[4][16 * 68];

    int t = threadIdx.x;
    int wid = t >> 6, lane = t & 63, quad = lane >> 4, l15 = lane & 15;
    int bh = blockIdx.x >> 4;
    int qtr = blockIdx.x & 15;
    int b = bh >> 3, h = bh & 7;
    int qt = (bh & 1) ? (15 - qtr) : qtr;
    int n0 = qt * 64;

    float gamma = 1.f - exp2f(-(float)(5 + h));
    float l2g = log2f(gamma);

    short8 aH[2], aL[2];
    {
        int qrow = b * 1024 + n0 + wid * 16 + l15;
        const float* qp = QKVG + (size_t)qrow * 2048 + h * 64;
#pragma unroll
        for (int ks = 0; ks < 2; ++ks) {
#pragma unroll
            for (int j = 0; j < 8; ++j) {
                float qv = qp[ks * 32 + quad * 8 + j];
                u16 hi, lo;
                splitbf(qv, hi, lo);
                aH[ks][j] = (short)hi;
                aL[ks][j] = (short)lo;
            }
        }
    }

    f32x4 yacc[4];
#pragma unroll
    for (int dt = 0; dt < 4; ++dt) yacc[dt] = (f32x4){0.f, 0.f, 0.f, 0.f};

    for (int mt = 0; mt <= qt; ++mt) {
        __syncthreads();
        // k tile row-major: b64 writes, conflict-free
        for (int c = t; c < 1024; c += 256) {
            int row = c >> 4, c4 = c & 15;
            size_t grow = (size_t)(b * 1024 + mt * 64 + row) * 2048;
            float4 kv = *(const float4*)&QKVG[grow + 512 + h * 64 + c4 * 4];
            unsigned p0 = splitbf2(kv.x), p1 = splitbf2(kv.y);
            unsigned p2 = splitbf2(kv.z), p3 = splitbf2(kv.w);
            us4 h4 = {(u16)p0, (u16)p1, (u16)p2, (u16)p3};
            us4 l4 = {(u16)(p0 >> 16), (u16)(p1 >> 16), (u16)(p2 >> 16), (u16)(p3 >> 16)};
            *(us4*)&kh[row * 72 + c4 * 4] = h4;
            *(us4*)&kl[row * 72 + c4 * 4] = l4;
        }
        // v^T tile: thread owns column d (coalesced global), 4 consecutive m, swizzled b64 write
        for (int c = t; c < 1024; c += 256) {
            int d = c & 63, mseg = c >> 6;
            size_t gbase = (size_t)(b * 1024 + mt * 64 + mseg * 4) * 2048 + 1024 + h * 64 + d;
            unsigned p0 = splitbf2(QKVG[gbase]);
            unsigned p1 = splitbf2(QKVG[gbase + 2048]);
            unsigned p2 = splitbf2(QKVG[gbase + 4096]);
            unsigned p3 = splitbf2(QKVG[gbase + 6144]);
            us4 h4 = {(u16)p0, (u16)p1, (u16)p2, (u16)p3};
            us4 l4 = {(u16)(p0 >> 16), (u16)(p1 >> 16), (u16)(p2 >> 16), (u16)(p3 >> 16)};
            int base = d * 72 + (((mseg >> 1) + d) & 7) * 8 + (mseg & 1) * 4;
            *(us4*)&vth[base] = h4;
            *(us4*)&vtl[base] = l4;
        }
        __syncthreads();

        // scores S[16 q-rows][64 m]
        f32x4 sacc[4];
#pragma unroll
        for (int tn = 0; tn < 4; ++tn) sacc[tn] = (f32x4){0.f, 0.f, 0.f, 0.f};
#pragma unroll
        for (int tn = 0; tn < 4; ++tn) {
#pragma unroll
            for (int ks = 0; ks < 2; ++ks) {
                short8 bH = *(const short8*)&kh[(tn * 16 + l15) * 72 + ks * 32 + quad * 8];
                short8 bL = *(const short8*)&kl[(tn * 16 + l15) * 72 + ks * 32 + quad * 8];
                sacc[tn] = __builtin_amdgcn_mfma_f32_16x16x32_bf16(aH[ks], bH, sacc[tn], 0, 0, 0);
                sacc[tn] = __builtin_amdgcn_mfma_f32_16x16x32_bf16(aL[ks], bH, sacc[tn], 0, 0, 0);
                sacc[tn] = __builtin_amdgcn_mfma_f32_16x16x32_bf16(aH[ks], bL, sacc[tn], 0, 0, 0);
            }
        }
        // decay -> P f32 (per-wave tile; wave-ordered DS, no barrier needed)
#pragma unroll
        for (int tn = 0; tn < 4; ++tn) {
            int mglob = mt * 64 + tn * 16 + l15;
#pragma unroll
            for (int r = 0; r < 4; ++r) {
                int nglob = n0 + wid * 16 + quad * 4 + r;
                int diff = nglob - mglob;
                float p = 0.f;
                if (diff >= 0) p = sacc[tn][r] * exp2f((float)diff * l2g - 3.0f);
                pf[wid][(quad * 4 + r) * 68 + tn * 16 + l15] = p;
            }
        }
        // P -> A-frags (split at read), then PV
        short8 pH[2], pL[2];
#pragma unroll
        for (int ks = 0; ks < 2; ++ks) {
            const float* pr = &pf[wid][l15 * 68 + ks * 32 + quad * 8];
#pragma unroll
            for (int j = 0; j < 8; ++j) {
                u16 hi, lo;
                splitbf(pr[j], hi, lo);
                pH[ks][j] = (short)hi;
                pL[ks][j] = (short)lo;
            }
        }
#pragma unroll
        for (int dt = 0; dt < 4; ++dt) {
            int d = dt * 16 + l15;
#pragma unroll
            for (int ks = 0; ks < 2; ++ks) {
                int vb = d * 72 + ((ks * 4 + quad + d) & 7) * 8;
                short8 vH = *(const short8*)&vth[vb];
                short8 vL = *(const short8*)&vtl[vb];
                yacc[dt] = __builtin_amdgcn_mfma_f32_16x16x32_bf16(pH[ks], vH, yacc[dt], 0, 0, 0);
                yacc[dt] = __builtin_amdgcn_mfma_f32_16x16x32_bf16(pL[ks], vH, yacc[dt], 0, 0, 0);
                yacc[dt] = __builtin_amdgcn_mfma_f32_16x16x32_bf16(pH[ks], vL, yacc[dt], 0, 0, 0);
            }
        }
    }

    // per-q-row groupnorm + swish gate + split store
#pragma unroll
    for (int r = 0; r < 4; ++r) {
        float s1 = yacc[0][r] + yacc[1][r] + yacc[2][r] + yacc[3][r];
        float s2 = yacc[0][r] * yacc[0][r] + yacc[1][r] * yacc[1][r] +
                   yacc[2][r] * yacc[2][r] + yacc[3][r] * yacc[3][r];
#pragma unroll
        for (int o = 1; o <= 8; o <<= 1) {
            s1 += __shfl_xor(s1, o, 64);
            s2 += __shfl_xor(s2, o, 64);
        }
        float mu = s1 * (1.f / 64.f);
        float var = fmaxf(s2 * (1.f / 64.f) - mu * mu, 0.f);
        float rs = 1.f / sqrtf(var + 1e-5f);
        int nglob = n0 + wid * 16 + quad * 4 + r;
        size_t grow = (size_t)(b * 1024 + nglob);
#pragma unroll
        for (int dt = 0; dt < 4; ++dt) {
            int d = dt * 16 + l15;
            float yv = (yacc[dt][r] - mu) * rs;
            float g = QKVG[grow * 2048 + 1536 + h * 64 + d];
            float sw = g / (1.f + expf(-g));
            float z = yv * sw;
            u16 hi, lo;
            splitbf(z, hi, lo);
            Zs[grow * 1024 + h * 64 + d] = hi;
            Zs[grow * 1024 + 512 + h * 64 + d] = lo;
        }
    }
}

// ---------- final FC ----------
__global__ __launch_bounds__(256) void fc_partial(const float* __restrict__ x3,
                                                  const float* __restrict__ fcW,
                                                  float* __restrict__ logits)
{
    __shared__ float red[4];
    int b = blockIdx.x >> 3, sl = blockIdx.x & 7;
    size_t xbase = (size_t)b * 524288 + (size_t)sl * 65536;
    size_t wbase = (size_t)sl * 65536;
    float s = 0.f;
    for (int i = threadIdx.x; i < 16384; i += 256) {
        float4 xv = *(const float4*)&x3[xbase + (size_t)i * 4];
        float4 wv = *(const float4*)&fcW[wbase + (size_t)i * 4];
        s += xv.x * wv.x + xv.y * wv.y + xv.z * wv.z + xv.w * wv.w;
    }
    int wid = threadIdx.x >> 6, lane = threadIdx.x & 63;
#pragma unroll
    for (int o = 32; o >= 1; o >>= 1) s += __shfl_xor(s, o, 64);
    if (lane == 0) red[wid] = s;
    __syncthreads();
    if (threadIdx.x == 0) atomicAdd(&logits[b], red[0] + red[1] + red[2] + red[3]);
}

__global__ void fc_final(const float* __restrict__ logits, const float* __restrict__ fcb,
                         float* __restrict__ out)
{
    int t = threadIdx.x;
    if (t < 8) {
        float l = logits[t] + fcb[0];
        out[t] = 1.f / (1.f + expf(-l));
    }
}

extern "C" void kernel_launch(void* const* d_in, const int* in_sizes, int n_in,
                              void* d_out, int out_size, void* d_ws, size_t ws_size,
                              hipStream_t stream)
{
    const int* ids = (const int*)d_in[0];
    const float* emb = (const float*)d_in[1];
    const float* pos = (const float*)d_in[2];
    const float* ln_g = (const float*)d_in[3];
    const float* ln_b = (const float*)d_in[4];
    const float* Wq = (const float*)d_in[5];
    const float* Wk = (const float*)d_in[6];
    const float* Wv = (const float*)d_in[7];
    const float* Wg = (const float*)d_in[8];
    const float* Wo = (const float*)d_in[9];
    const float* W1 = (const float*)d_in[10];
    const float* b1 = (const float*)d_in[11];
    const float* W2 = (const float*)d_in[12];
    const float* b2 = (const float*)d_in[13];
    const float* fcW = (const float*)d_in[14];
    const float* fcb = (const float*)d_in[15];
    float* out = (float*)d_out;

    char* ws = (char*)d_ws;
    u16* WTh    = (u16*)(ws);                  //  3,670,016
    u16* WTl    = (u16*)(ws + 3670016);        //  3,670,016
    float* x0f  = (float*)(ws + 7340032);      // 16,777,216  LN(emb) f32 (residual)
    u16* x0s    = (u16*)(ws + 24117248);       // 16,777,216  LN(emb) split
    float* QKVG = (float*)(ws + 40894464);     // 67,108,864  [8192][2048]
    float* logits = (float*)(ws + 108003328);  // 32 B (total 108 MB, < proven 117.4 MB)
    u16* Zs   = x0s;                            // x0s dead after QKVG GEMM
    float* X1 = QKVG;                           // QKVG dead after retention
    u16* Ts   = (u16*)((char*)QKVG + 16777216);
    u16* Hs   = (u16*)((char*)QKVG + 33554432);
    float* X3 = (float*)((char*)QKVG + 50331648);
    float* X2 = x0f;                            // x0f dead after Wo-GEMM residual

    // only vocab iteration i=2 is live (x overwritten each pass)
    transpose_w<<<dim3(8, 8, 7), 256, 0, stream>>>(Wq, Wk, Wv, Wg, Wo, W1, W2, WTh, WTl);
    ln_kernel<<<8192, 256, 0, stream>>>(nullptr, ids, emb, pos, ln_g, ln_b, x0f, x0s, 1, nullptr);
    gemm_split<<<dim3(16, 64), 256, 0, stream>>>(x0s, WTh, WTl, QKVG, nullptr, nullptr, nullptr, 0, 2048);
    retention_mfma<<<1024, 256, 0, stream>>>(QKVG, Zs);
    gemm_split<<<dim3(4, 64), 256, 0, stream>>>(Zs, WTh + 4 * 262144, WTl + 4 * 262144, X1, nullptr, x0f, nullptr, 1, 512);
    ln_kernel<<<8192, 256, 0, stream>>>(X1, nullptr, nullptr, nullptr, ln_g, ln_b, nullptr, Ts, 0, nullptr);
    gemm_split<<<dim3(4, 64), 256, 0, stream>>>(Ts, WTh + 5 * 262144, WTl + 5 * 262144, nullptr, Hs, nullptr, b1, 2, 512);
    gemm_split<<<dim3(4, 64), 256, 0, stream>>>(Hs, WTh + 6 * 262144, WTl + 6 * 262144, X2, nullptr, X1, b2, 3, 512);
    ln_kernel<<<8192, 256, 0, stream>>>(X2, nullptr, nullptr, nullptr, ln_g, ln_b, X3, nullptr, 0, logits);
    fc_partial<<<64, 256, 0, stream>>>(X3, fcW, logits);
    fc_final<<<1, 64, 0, stream>>>(logits, fcb, out);
}

// Round 8
// 389.655 us; speedup vs baseline: 1.4046x; 1.4046x over previous
//
#include <hip/hip_runtime.h>
#include <math.h>

typedef unsigned short u16;
typedef __attribute__((ext_vector_type(8))) _Float16 half8;
typedef __attribute__((ext_vector_type(8))) short short8;
typedef __attribute__((ext_vector_type(4))) float f32x4;
typedef __attribute__((ext_vector_type(4))) unsigned short us4;

// Inputs f32, output f32 (proven rounds 4-7). Numeric format: f16 (11-bit mantissa).
// Activations: single f16. Weights: hi/lo f16 split (2-term MFMA). Error budget:
// ~5e-4 rel/layer -> logit err ~0.017 -> sigmoid err <= 0.004 << 2e-2 threshold.

static __device__ __forceinline__ u16 f2h(float f) {
    _Float16 h = (_Float16)f;
    return __builtin_bit_cast(u16, h);
}
static __device__ __forceinline__ float h2f(u16 u) {
    return (float)__builtin_bit_cast(_Float16, u);
}

// ---------- weight transpose+split: WTh/WTl[w][n][k] = f16split(W[w][k][n]) ----------
__global__ __launch_bounds__(256) void transpose_w(
    const float* __restrict__ Wq, const float* __restrict__ Wk, const float* __restrict__ Wv,
    const float* __restrict__ Wg, const float* __restrict__ Wo, const float* __restrict__ W1,
    const float* __restrict__ W2, u16* __restrict__ WTh, u16* __restrict__ WTl)
{
    __shared__ float tile[64][65];
    const float* Ws[7] = {Wq, Wk, Wv, Wg, Wo, W1, W2};
    int w = blockIdx.z;
    int k0 = blockIdx.x * 64, n0 = blockIdx.y * 64;
    const float* W = Ws[w];
    int t = threadIdx.x;
    for (int c = t; c < 4096; c += 256) {
        int row = c >> 6, col = c & 63;
        tile[row][col] = W[(size_t)(k0 + row) * 512 + n0 + col];
    }
    __syncthreads();
    for (int c = t; c < 4096; c += 256) {
        int row = c >> 6, col = c & 63;
        float v = tile[col][row];
        u16 hi = f2h(v);
        u16 lo = f2h(v - h2f(hi));
        size_t o = (size_t)w * 262144 + (size_t)(n0 + row) * 512 + k0 + col;
        WTh[o] = hi;
        WTl[o] = lo;
    }
}

// ---------- LayerNorm; writes f32 and/or f16 [row][512] ----------
__global__ __launch_bounds__(256) void ln_kernel(
    const float* __restrict__ xin,
    const int* __restrict__ ids, const float* __restrict__ emb, const float* __restrict__ pos,
    const float* __restrict__ gam, const float* __restrict__ bet,
    float* __restrict__ outf, u16* __restrict__ outh, int mode, float* __restrict__ zero8)
{
    __shared__ float red[8];
    int row = blockIdx.x, t = threadIdx.x;
    int wid = t >> 6, lane = t & 63;
    float v0, v1;
    if (mode == 1) {
        int id = ids[2 * 8192 + row];
        const float* e = emb + (size_t)(2 * 1024 + id) * 512;
        const float* p = pos + (size_t)(2 * 1024 + (row & 1023)) * 512;
        v0 = e[t] + p[t];
        v1 = e[t + 256] + p[t + 256];
    } else {
        v0 = xin[(size_t)row * 512 + t];
        v1 = xin[(size_t)row * 512 + t + 256];
    }
    float s1 = v0 + v1, s2 = v0 * v0 + v1 * v1;
#pragma unroll
    for (int o = 32; o >= 1; o >>= 1) {
        s1 += __shfl_xor(s1, o, 64);
        s2 += __shfl_xor(s2, o, 64);
    }
    if (lane == 0) { red[wid] = s1; red[4 + wid] = s2; }
    __syncthreads();
    float S1 = red[0] + red[1] + red[2] + red[3];
    float S2 = red[4] + red[5] + red[6] + red[7];
    float mu = S1 * (1.f / 512.f);
    float var = fmaxf(S2 * (1.f / 512.f) - mu * mu, 0.f);
    float rs = 1.f / sqrtf(var + 1e-5f);
    float y0 = (v0 - mu) * rs * gam[t] + bet[t];
    float y1 = (v1 - mu) * rs * gam[t + 256] + bet[t + 256];
    if (outf) {
        outf[(size_t)row * 512 + t] = y0;
        outf[(size_t)row * 512 + t + 256] = y1;
    }
    if (outh) {
        outh[(size_t)row * 512 + t] = f2h(y0);
        outh[(size_t)row * 512 + t + 256] = f2h(y1);
    }
    if (zero8 && row == 0 && t < 8) zero8[t] = 0.f;
}

// ---------- GEMM: C = A_f16 x (Bh + Bl)^T ; 2-term f16 MFMA; 16 k-iters ----------
// mode 0: outf=C ; 1: outf=C+res ; 2: outh=f16(relu(C+bias)) ; 3: outf=C+bias+res
__global__ __launch_bounds__(256) void gemm_f16(
    const u16* __restrict__ A2, const u16* __restrict__ Bhg, const u16* __restrict__ Blg,
    float* __restrict__ outf, u16* __restrict__ outh,
    const float* __restrict__ res, const float* __restrict__ bias, int mode, int ostride)
{
    __shared__ u16 As[128 * 40];
    __shared__ u16 Bh[128 * 40];
    __shared__ u16 Bl[128 * 40];
    int t = threadIdx.x;
    int wid = t >> 6, lane = t & 63, quad = lane >> 4, l15 = lane & 15;
    int wm = wid >> 1, wn = wid & 1;
    int m0 = blockIdx.y * 128, n0 = blockIdx.x * 128;

    f32x4 acc[4][4];
#pragma unroll
    for (int a = 0; a < 4; ++a)
#pragma unroll
        for (int b = 0; b < 4; ++b) acc[a][b] = (f32x4){0.f, 0.f, 0.f, 0.f};

    for (int ki = 0; ki < 16; ++ki) {
        int k0 = ki * 32;
        __syncthreads();
#pragma unroll
        for (int i = 0; i < 2; ++i) {
            int c = t + i * 256;
            int row = c >> 2, part = c & 3;
            *(short8*)&As[row * 40 + part * 8] =
                *(const short8*)&A2[(size_t)(m0 + row) * 512 + k0 + part * 8];
            *(short8*)&Bh[row * 40 + part * 8] =
                *(const short8*)&Bhg[(size_t)(n0 + row) * 512 + k0 + part * 8];
            *(short8*)&Bl[row * 40 + part * 8] =
                *(const short8*)&Blg[(size_t)(n0 + row) * 512 + k0 + part * 8];
        }
        __syncthreads();
        half8 af[4], bhv[4], blv[4];
#pragma unroll
        for (int tm = 0; tm < 4; ++tm)
            af[tm] = *(const half8*)&As[(wm * 64 + tm * 16 + l15) * 40 + quad * 8];
#pragma unroll
        for (int tn = 0; tn < 4; ++tn) {
            bhv[tn] = *(const half8*)&Bh[(wn * 64 + tn * 16 + l15) * 40 + quad * 8];
            blv[tn] = *(const half8*)&Bl[(wn * 64 + tn * 16 + l15) * 40 + quad * 8];
        }
#pragma unroll
        for (int tm = 0; tm < 4; ++tm)
#pragma unroll
            for (int tn = 0; tn < 4; ++tn) {
                acc[tm][tn] = __builtin_amdgcn_mfma_f32_16x16x32_f16(af[tm], bhv[tn], acc[tm][tn], 0, 0, 0);
                acc[tm][tn] = __builtin_amdgcn_mfma_f32_16x16x32_f16(af[tm], blv[tn], acc[tm][tn], 0, 0, 0);
            }
    }

#pragma unroll
    for (int tm = 0; tm < 4; ++tm) {
#pragma unroll
        for (int tn = 0; tn < 4; ++tn) {
            int n = n0 + wn * 64 + tn * 16 + l15;
            int mbase = m0 + wm * 64 + tm * 16 + quad * 4;
#pragma unroll
            for (int r = 0; r < 4; ++r) {
                int m = mbase + r;
                float v = acc[tm][tn][r];
                if (mode == 1) v += res[(size_t)m * 512 + n];
                else if (mode == 2) v = fmaxf(v + bias[n], 0.f);
                else if (mode == 3) v += bias[n] + res[(size_t)m * 512 + n];
                if (mode == 2) outh[(size_t)m * 512 + n] = f2h(v);
                else outf[(size_t)m * ostride + n] = v;
            }
        }
    }
}

// ---------- fused retention, q-tile=128 rows/block (4 waves x 32 rows) ----------
// single-f16 operands; V^T rotation-swizzled; P tile f16 per-wave (b128-friendly).
__global__ __launch_bounds__(256) void retention_f16(
    const float* __restrict__ QKVG, u16* __restrict__ Zh)
{
    __shared__ u16 kh[64 * 72];        // K tile [m][d] f16
    __shared__ u16 vth[64 * 72];       // V^T tile [d][m] f16, swizzled
    __shared__ u16 ph[4][32 * 72];     // per-wave P [qrow][m] f16

    int t = threadIdx.x;
    int wid = t >> 6, lane = t & 63, quad = lane >> 4, l15 = lane & 15;
    int bh = (blockIdx.x >> 3) & 63;
    int qtr = blockIdx.x & 7;
    int b = bh >> 3, h = bh & 7;
    // balance: blocks i and i+256 (likely same CU) get complementary qt
    int qt = ((blockIdx.x >> 8) & 1) ? (7 - qtr) : qtr;
    int n0 = qt * 128;

    float gamma = 1.f - exp2f(-(float)(5 + h));
    float l2g = log2f(gamma);

    // Q frags (A-layout: row=l15, k=quad*8+j), 2 groups of 16 q-rows per wave
    half8 aH[2][2];
#pragma unroll
    for (int g = 0; g < 2; ++g) {
        int qrow = b * 1024 + n0 + wid * 32 + g * 16 + l15;
        const float* qp = QKVG + (size_t)qrow * 2048 + h * 64;
#pragma unroll
        for (int ks = 0; ks < 2; ++ks)
#pragma unroll
            for (int j = 0; j < 8; ++j)
                aH[g][ks][j] = (_Float16)qp[ks * 32 + quad * 8 + j];
    }

    f32x4 yacc[2][4];
#pragma unroll
    for (int g = 0; g < 2; ++g)
#pragma unroll
        for (int dt = 0; dt < 4; ++dt) yacc[g][dt] = (f32x4){0.f, 0.f, 0.f, 0.f};

    int mt_end = 2 * qt + 1;
    for (int mt = 0; mt <= mt_end; ++mt) {
        __syncthreads();
        // K tile: row-major, b64 writes, conflict-free
        for (int c = t; c < 1024; c += 256) {
            int row = c >> 4, c4 = c & 15;
            size_t grow = (size_t)(b * 1024 + mt * 64 + row) * 2048;
            const float4 kv = *(const float4*)&QKVG[grow + 512 + h * 64 + c4 * 4];
            us4 k4 = {f2h(kv.x), f2h(kv.y), f2h(kv.z), f2h(kv.w)};
            *(us4*)&kh[row * 72 + c4 * 4] = k4;
        }
        // V^T tile: thread owns column d, 4 consecutive m, rotation-swizzled b64 write
        for (int c = t; c < 1024; c += 256) {
            int d = c & 63, mseg = c >> 6;
            size_t gbase = (size_t)(b * 1024 + mt * 64 + mseg * 4) * 2048 + 1024 + h * 64 + d;
            us4 v4 = {f2h(QKVG[gbase]), f2h(QKVG[gbase + 2048]),
                      f2h(QKVG[gbase + 4096]), f2h(QKVG[gbase + 6144])};
            int base = d * 72 + (((mseg >> 1) + d) & 7) * 8 + (mseg & 1) * 4;
            *(us4*)&vth[base] = v4;
        }
        __syncthreads();

        // scores + decay -> P (per group), single f16 term
#pragma unroll
        for (int g = 0; g < 2; ++g) {
            f32x4 sacc[4];
#pragma unroll
            for (int tn = 0; tn < 4; ++tn) sacc[tn] = (f32x4){0.f, 0.f, 0.f, 0.f};
#pragma unroll
            for (int tn = 0; tn < 4; ++tn)
#pragma unroll
                for (int ks = 0; ks < 2; ++ks) {
                    half8 bH = *(const half8*)&kh[(tn * 16 + l15) * 72 + ks * 32 + quad * 8];
                    sacc[tn] = __builtin_amdgcn_mfma_f32_16x16x32_f16(aH[g][ks], bH, sacc[tn], 0, 0, 0);
                }
#pragma unroll
            for (int tn = 0; tn < 4; ++tn) {
                int mglob = mt * 64 + tn * 16 + l15;          // D col
#pragma unroll
                for (int r = 0; r < 4; ++r) {
                    int nglob = n0 + wid * 32 + g * 16 + quad * 4 + r;  // D row
                    int diff = nglob - mglob;
                    float p = (diff >= 0) ? sacc[tn][r] * exp2f((float)diff * l2g - 3.0f) : 0.f;
                    ph[wid][(g * 16 + quad * 4 + r) * 72 + tn * 16 + l15] = f2h(p);
                }
            }
        }
        // PV (per-wave P; DS within-wave ordered, no barrier needed)
#pragma unroll
        for (int g = 0; g < 2; ++g) {
            half8 pH0 = *(const half8*)&ph[wid][(g * 16 + l15) * 72 + quad * 8];
            half8 pH1 = *(const half8*)&ph[wid][(g * 16 + l15) * 72 + 32 + quad * 8];
#pragma unroll
            for (int dt = 0; dt < 4; ++dt) {
                int d = dt * 16 + l15;
                half8 v0 = *(const half8*)&vth[d * 72 + ((quad + d) & 7) * 8];
                half8 v1 = *(const half8*)&vth[d * 72 + ((4 + quad + d) & 7) * 8];
                yacc[g][dt] = __builtin_amdgcn_mfma_f32_16x16x32_f16(pH0, v0, yacc[g][dt], 0, 0, 0);
                yacc[g][dt] = __builtin_amdgcn_mfma_f32_16x16x32_f16(pH1, v1, yacc[g][dt], 0, 0, 0);
            }
        }
    }

    // per-q-row groupnorm + swish gate + f16 store
#pragma unroll
    for (int g = 0; g < 2; ++g) {
#pragma unroll
        for (int r = 0; r < 4; ++r) {
            float s1 = yacc[g][0][r] + yacc[g][1][r] + yacc[g][2][r] + yacc[g][3][r];
            float s2 = yacc[g][0][r] * yacc[g][0][r] + yacc[g][1][r] * yacc[g][1][r] +
                       yacc[g][2][r] * yacc[g][2][r] + yacc[g][3][r] * yacc[g][3][r];
#pragma unroll
            for (int o = 1; o <= 8; o <<= 1) {
                s1 += __shfl_xor(s1, o, 64);
                s2 += __shfl_xor(s2, o, 64);
            }
            float mu = s1 * (1.f / 64.f);
            float var = fmaxf(s2 * (1.f / 64.f) - mu * mu, 0.f);
            float rs = 1.f / sqrtf(var + 1e-5f);
            int nglob = n0 + wid * 32 + g * 16 + quad * 4 + r;
            size_t grow = (size_t)(b * 1024 + nglob);
#pragma unroll
            for (int dt = 0; dt < 4; ++dt) {
                int d = dt * 16 + l15;
                float yv = (yacc[g][dt][r] - mu) * rs;
                float gt = QKVG[grow * 2048 + 1536 + h * 64 + d];
                float sw = gt / (1.f + expf(-gt));
                Zh[grow * 512 + h * 64 + d] = f2h(yv * sw);
            }
        }
    }
}

// ---------- final FC ----------
__global__ __launch_bounds__(256) void fc_partial(const float* __restrict__ x3,
                                                  const float* __restrict__ fcW,
                                                  float* __restrict__ logits)
{
    __shared__ float red[4];
    int b = blockIdx.x >> 3, sl = blockIdx.x & 7;
    size_t xbase = (size_t)b * 524288 + (size_t)sl * 65536;
    size_t wbase = (size_t)sl * 65536;
    float s = 0.f;
    for (int i = threadIdx.x; i < 16384; i += 256) {
        float4 xv = *(const float4*)&x3[xbase + (size_t)i * 4];
        float4 wv = *(const float4*)&fcW[wbase + (size_t)i * 4];
        s += xv.x * wv.x + xv.y * wv.y + xv.z * wv.z + xv.w * wv.w;
    }
    int wid = threadIdx.x >> 6, lane = threadIdx.x & 63;
#pragma unroll
    for (int o = 32; o >= 1; o >>= 1) s += __shfl_xor(s, o, 64);
    if (lane == 0) red[wid] = s;
    __syncthreads();
    if (threadIdx.x == 0) atomicAdd(&logits[b], red[0] + red[1] + red[2] + red[3]);
}

__global__ void fc_final(const float* __restrict__ logits, const float* __restrict__ fcb,
                         float* __restrict__ out)
{
    int t = threadIdx.x;
    if (t < 8) {
        float l = logits[t] + fcb[0];
        out[t] = 1.f / (1.f + expf(-l));
    }
}

extern "C" void kernel_launch(void* const* d_in, const int* in_sizes, int n_in,
                              void* d_out, int out_size, void* d_ws, size_t ws_size,
                              hipStream_t stream)
{
    const int* ids = (const int*)d_in[0];
    const float* emb = (const float*)d_in[1];
    const float* pos = (const float*)d_in[2];
    const float* ln_g = (const float*)d_in[3];
    const float* ln_b = (const float*)d_in[4];
    const float* Wq = (const float*)d_in[5];
    const float* Wk = (const float*)d_in[6];
    const float* Wv = (const float*)d_in[7];
    const float* Wg = (const float*)d_in[8];
    const float* Wo = (const float*)d_in[9];
    const float* W1 = (const float*)d_in[10];
    const float* b1 = (const float*)d_in[11];
    const float* W2 = (const float*)d_in[12];
    const float* b2 = (const float*)d_in[13];
    const float* fcW = (const float*)d_in[14];
    const float* fcb = (const float*)d_in[15];
    float* out = (float*)d_out;

    char* ws = (char*)d_ws;
    u16* WTh    = (u16*)(ws);                  //  3,670,016
    u16* WTl    = (u16*)(ws + 3670016);        //  3,670,016
    float* x0f  = (float*)(ws + 7340032);      // 16,777,216  LN(emb) f32 (residual)
    u16* x0h    = (u16*)(ws + 24117248);       //  8,388,608  LN(emb) f16
    float* QKVG = (float*)(ws + 32505856);     // 67,108,864  [8192][2048]
    float* logits = (float*)(ws + 99614720);   // 32 B  (total ~99.6 MB)
    u16* Zh   = x0h;                            // dead after QKVG GEMM
    float* X1 = QKVG;                           // QKVG dead after retention
    u16* Th   = (u16*)((char*)QKVG + 16777216);
    u16* Hh   = (u16*)((char*)QKVG + 25165824);
    float* X3 = (float*)((char*)QKVG + 33554432);
    float* X2 = x0f;                            // dead after Wo-GEMM residual

    // only vocab iteration i=2 is live (x overwritten each pass)
    transpose_w<<<dim3(8, 8, 7), 256, 0, stream>>>(Wq, Wk, Wv, Wg, Wo, W1, W2, WTh, WTl);
    ln_kernel<<<8192, 256, 0, stream>>>(nullptr, ids, emb, pos, ln_g, ln_b, x0f, x0h, 1, nullptr);
    gemm_f16<<<dim3(16, 64), 256, 0, stream>>>(x0h, WTh, WTl, QKVG, nullptr, nullptr, nullptr, 0, 2048);
    retention_f16<<<512, 256, 0, stream>>>(QKVG, Zh);
    gemm_f16<<<dim3(4, 64), 256, 0, stream>>>(Zh, WTh + 4 * 262144, WTl + 4 * 262144, X1, nullptr, x0f, nullptr, 1, 512);
    ln_kernel<<<8192, 256, 0, stream>>>(X1, nullptr, nullptr, nullptr, ln_g, ln_b, nullptr, Th, 0, nullptr);
    gemm_f16<<<dim3(4, 64), 256, 0, stream>>>(Th, WTh + 5 * 262144, WTl + 5 * 262144, nullptr, Hh, nullptr, b1, 2, 512);
    gemm_f16<<<dim3(4, 64), 256, 0, stream>>>(Hh, WTh + 6 * 262144, WTl + 6 * 262144, X2, nullptr, X1, b2, 3, 512);
    ln_kernel<<<8192, 256, 0, stream>>>(X2, nullptr, nullptr, nullptr, ln_g, ln_b, X3, nullptr, 0, logits);
    fc_partial<<<64, 256, 0, stream>>>(X3, fcW, logits);
    fc_final<<<1, 64, 0, stream>>>(logits, fcb, out);
}

// Round 9
// 358.201 us; speedup vs baseline: 1.5279x; 1.0878x over previous
//
#include <hip/hip_runtime.h>
#include <math.h>

typedef unsigned short u16;
typedef __attribute__((ext_vector_type(8))) _Float16 half8;
typedef __attribute__((ext_vector_type(8))) short short8;
typedef __attribute__((ext_vector_type(4))) float f32x4;
typedef __attribute__((ext_vector_type(4))) unsigned short us4;

// Inputs f32, output f32 (proven r4-8). Format: f16 single-term everywhere.
// r8 measured absmax 2.4e-4 with split weights; single-f16 weights predicted ~5e-4
// (weight f16 rel err 4.9e-4, uncorrelated over K) — 40x under the 2e-2 threshold.

static __device__ __forceinline__ u16 f2h(float f) {
    _Float16 h = (_Float16)f;
    return __builtin_bit_cast(u16, h);
}
static __device__ __forceinline__ float h2f(u16 u) {
    return (float)__builtin_bit_cast(_Float16, u);
}

// ---------- weight transpose: WT[w][n][k] = f16(W[w][k][n]) ----------
__global__ __launch_bounds__(256) void transpose_w(
    const float* __restrict__ Wq, const float* __restrict__ Wk, const float* __restrict__ Wv,
    const float* __restrict__ Wg, const float* __restrict__ Wo, const float* __restrict__ W1,
    const float* __restrict__ W2, u16* __restrict__ WT)
{
    __shared__ float tile[64][65];
    const float* Ws[7] = {Wq, Wk, Wv, Wg, Wo, W1, W2};
    int w = blockIdx.z;
    int k0 = blockIdx.x * 64, n0 = blockIdx.y * 64;
    const float* W = Ws[w];
    int t = threadIdx.x;
    for (int c = t; c < 4096; c += 256) {
        int row = c >> 6, col = c & 63;
        tile[row][col] = W[(size_t)(k0 + row) * 512 + n0 + col];
    }
    __syncthreads();
    for (int c = t; c < 4096; c += 256) {
        int row = c >> 6, col = c & 63;
        WT[(size_t)w * 262144 + (size_t)(n0 + row) * 512 + k0 + col] = f2h(tile[col][row]);
    }
}

// ---------- LayerNorm; writes f32 and/or f16 [row][512] ----------
__global__ __launch_bounds__(256) void ln_kernel(
    const float* __restrict__ xin,
    const int* __restrict__ ids, const float* __restrict__ emb, const float* __restrict__ pos,
    const float* __restrict__ gam, const float* __restrict__ bet,
    float* __restrict__ outf, u16* __restrict__ outh, int mode, float* __restrict__ zero8)
{
    __shared__ float red[8];
    int row = blockIdx.x, t = threadIdx.x;
    int wid = t >> 6, lane = t & 63;
    float v0, v1;
    if (mode == 1) {
        int id = ids[2 * 8192 + row];
        const float* e = emb + (size_t)(2 * 1024 + id) * 512;
        const float* p = pos + (size_t)(2 * 1024 + (row & 1023)) * 512;
        v0 = e[t] + p[t];
        v1 = e[t + 256] + p[t + 256];
    } else {
        v0 = xin[(size_t)row * 512 + t];
        v1 = xin[(size_t)row * 512 + t + 256];
    }
    float s1 = v0 + v1, s2 = v0 * v0 + v1 * v1;
#pragma unroll
    for (int o = 32; o >= 1; o >>= 1) {
        s1 += __shfl_xor(s1, o, 64);
        s2 += __shfl_xor(s2, o, 64);
    }
    if (lane == 0) { red[wid] = s1; red[4 + wid] = s2; }
    __syncthreads();
    float S1 = red[0] + red[1] + red[2] + red[3];
    float S2 = red[4] + red[5] + red[6] + red[7];
    float mu = S1 * (1.f / 512.f);
    float var = fmaxf(S2 * (1.f / 512.f) - mu * mu, 0.f);
    float rs = 1.f / sqrtf(var + 1e-5f);
    float y0 = (v0 - mu) * rs * gam[t] + bet[t];
    float y1 = (v1 - mu) * rs * gam[t + 256] + bet[t + 256];
    if (outf) {
        outf[(size_t)row * 512 + t] = y0;
        outf[(size_t)row * 512 + t + 256] = y1;
    }
    if (outh) {
        outh[(size_t)row * 512 + t] = f2h(y0);
        outh[(size_t)row * 512 + t + 256] = f2h(y1);
    }
    if (zero8 && row == 0 && t < 8) zero8[t] = 0.f;
}

// ---------- GEMM: C = A_f16 x B_f16^T ; single-term f16 MFMA; 16 k-iters ----------
// mode 0: outf=C ; 1: outf=C+res ; 2: outh=f16(relu(C+bias)) ; 3: outf=C+bias+res ;
// 4: outh=f16(C) at ostride (QKVG path)
__global__ __launch_bounds__(256) void gemm_f16(
    const u16* __restrict__ A2, const u16* __restrict__ Bg,
    float* __restrict__ outf, u16* __restrict__ outh,
    const float* __restrict__ res, const float* __restrict__ bias, int mode, int ostride)
{
    __shared__ u16 As[128 * 40];
    __shared__ u16 Bs[128 * 40];
    int t = threadIdx.x;
    int wid = t >> 6, lane = t & 63, quad = lane >> 4, l15 = lane & 15;
    int wm = wid >> 1, wn = wid & 1;
    int m0 = blockIdx.y * 128, n0 = blockIdx.x * 128;

    f32x4 acc[4][4];
#pragma unroll
    for (int a = 0; a < 4; ++a)
#pragma unroll
        for (int b = 0; b < 4; ++b) acc[a][b] = (f32x4){0.f, 0.f, 0.f, 0.f};

    for (int ki = 0; ki < 16; ++ki) {
        int k0 = ki * 32;
        __syncthreads();
#pragma unroll
        for (int i = 0; i < 2; ++i) {
            int c = t + i * 256;
            int row = c >> 2, part = c & 3;
            *(short8*)&As[row * 40 + part * 8] =
                *(const short8*)&A2[(size_t)(m0 + row) * 512 + k0 + part * 8];
            *(short8*)&Bs[row * 40 + part * 8] =
                *(const short8*)&Bg[(size_t)(n0 + row) * 512 + k0 + part * 8];
        }
        __syncthreads();
        half8 af[4], bf[4];
#pragma unroll
        for (int tm = 0; tm < 4; ++tm)
            af[tm] = *(const half8*)&As[(wm * 64 + tm * 16 + l15) * 40 + quad * 8];
#pragma unroll
        for (int tn = 0; tn < 4; ++tn)
            bf[tn] = *(const half8*)&Bs[(wn * 64 + tn * 16 + l15) * 40 + quad * 8];
#pragma unroll
        for (int tm = 0; tm < 4; ++tm)
#pragma unroll
            for (int tn = 0; tn < 4; ++tn)
                acc[tm][tn] = __builtin_amdgcn_mfma_f32_16x16x32_f16(af[tm], bf[tn], acc[tm][tn], 0, 0, 0);
    }

#pragma unroll
    for (int tm = 0; tm < 4; ++tm) {
#pragma unroll
        for (int tn = 0; tn < 4; ++tn) {
            int n = n0 + wn * 64 + tn * 16 + l15;
            int mbase = m0 + wm * 64 + tm * 16 + quad * 4;
#pragma unroll
            for (int r = 0; r < 4; ++r) {
                int m = mbase + r;
                float v = acc[tm][tn][r];
                if (mode == 1) v += res[(size_t)m * 512 + n];
                else if (mode == 2) v = fmaxf(v + bias[n], 0.f);
                else if (mode == 3) v += bias[n] + res[(size_t)m * 512 + n];
                if (mode == 2) outh[(size_t)m * 512 + n] = f2h(v);
                else if (mode == 4) outh[(size_t)m * ostride + n] = f2h(v);
                else outf[(size_t)m * ostride + n] = v;
            }
        }
    }
}

// ---------- fused retention, q-tile=128 (4 waves x 32 rows); QKVG in f16 ----------
__global__ __launch_bounds__(256) void retention_f16(
    const u16* __restrict__ QKVGh, u16* __restrict__ Zh)
{
    __shared__ u16 kh[64 * 72];        // K tile [m][d]
    __shared__ u16 vth[64 * 72];       // V^T tile [d][m], rotation-swizzled
    __shared__ u16 ph[4][32 * 72];     // per-wave P [qrow][m]

    int t = threadIdx.x;
    int wid = t >> 6, lane = t & 63, quad = lane >> 4, l15 = lane & 15;
    int bh = (blockIdx.x >> 3) & 63;
    int qtr = blockIdx.x & 7;
    int b = bh >> 3, h = bh & 7;
    int qt = ((blockIdx.x >> 8) & 1) ? (7 - qtr) : qtr;  // pairing balance
    int n0 = qt * 128;

    float gamma = 1.f - exp2f(-(float)(5 + h));
    float l2g = log2f(gamma);

    // Q frags: direct half8 loads (A-layout row=l15, k=quad*8+j)
    half8 aH[2][2];
#pragma unroll
    for (int g = 0; g < 2; ++g) {
        int qrow = b * 1024 + n0 + wid * 32 + g * 16 + l15;
        const u16* qp = QKVGh + (size_t)qrow * 2048 + h * 64;
#pragma unroll
        for (int ks = 0; ks < 2; ++ks)
            aH[g][ks] = *(const half8*)&qp[ks * 32 + quad * 8];
    }

    f32x4 yacc[2][4];
#pragma unroll
    for (int g = 0; g < 2; ++g)
#pragma unroll
        for (int dt = 0; dt < 4; ++dt) yacc[g][dt] = (f32x4){0.f, 0.f, 0.f, 0.f};

    int mt_end = 2 * qt + 1;
    for (int mt = 0; mt <= mt_end; ++mt) {
        __syncthreads();
        // K tile: straight us4 copies (no convert)
        for (int c = t; c < 1024; c += 256) {
            int row = c >> 4, c4 = c & 15;
            size_t grow = (size_t)(b * 1024 + mt * 64 + row) * 2048;
            *(us4*)&kh[row * 72 + c4 * 4] = *(const us4*)&QKVGh[grow + 512 + h * 64 + c4 * 4];
        }
        // V^T tile: thread owns column d, 4 consecutive m, rotation-swizzled b64 write
        for (int c = t; c < 1024; c += 256) {
            int d = c & 63, mseg = c >> 6;
            size_t gbase = (size_t)(b * 1024 + mt * 64 + mseg * 4) * 2048 + 1024 + h * 64 + d;
            us4 v4 = {QKVGh[gbase], QKVGh[gbase + 2048],
                      QKVGh[gbase + 4096], QKVGh[gbase + 6144]};
            int base = d * 72 + (((mseg >> 1) + d) & 7) * 8 + (mseg & 1) * 4;
            *(us4*)&vth[base] = v4;
        }
        __syncthreads();

        // scores + decay -> P per group
#pragma unroll
        for (int g = 0; g < 2; ++g) {
            f32x4 sacc[4];
#pragma unroll
            for (int tn = 0; tn < 4; ++tn) sacc[tn] = (f32x4){0.f, 0.f, 0.f, 0.f};
#pragma unroll
            for (int tn = 0; tn < 4; ++tn)
#pragma unroll
                for (int ks = 0; ks < 2; ++ks) {
                    half8 bH = *(const half8*)&kh[(tn * 16 + l15) * 72 + ks * 32 + quad * 8];
                    sacc[tn] = __builtin_amdgcn_mfma_f32_16x16x32_f16(aH[g][ks], bH, sacc[tn], 0, 0, 0);
                }
#pragma unroll
            for (int tn = 0; tn < 4; ++tn) {
                int mglob = mt * 64 + tn * 16 + l15;          // D col
#pragma unroll
                for (int r = 0; r < 4; ++r) {
                    int nglob = n0 + wid * 32 + g * 16 + quad * 4 + r;  // D row
                    int diff = nglob - mglob;
                    float p = (diff >= 0) ? sacc[tn][r] * exp2f((float)diff * l2g - 3.0f) : 0.f;
                    ph[wid][(g * 16 + quad * 4 + r) * 72 + tn * 16 + l15] = f2h(p);
                }
            }
        }
        // PV (per-wave P; within-wave DS ordering, no barrier)
#pragma unroll
        for (int g = 0; g < 2; ++g) {
            half8 pH0 = *(const half8*)&ph[wid][(g * 16 + l15) * 72 + quad * 8];
            half8 pH1 = *(const half8*)&ph[wid][(g * 16 + l15) * 72 + 32 + quad * 8];
#pragma unroll
            for (int dt = 0; dt < 4; ++dt) {
                int d = dt * 16 + l15;
                half8 v0 = *(const half8*)&vth[d * 72 + ((quad + d) & 7) * 8];
                half8 v1 = *(const half8*)&vth[d * 72 + ((4 + quad + d) & 7) * 8];
                yacc[g][dt] = __builtin_amdgcn_mfma_f32_16x16x32_f16(pH0, v0, yacc[g][dt], 0, 0, 0);
                yacc[g][dt] = __builtin_amdgcn_mfma_f32_16x16x32_f16(pH1, v1, yacc[g][dt], 0, 0, 0);
            }
        }
    }

    // per-q-row groupnorm + swish gate + f16 store
#pragma unroll
    for (int g = 0; g < 2; ++g) {
#pragma unroll
        for (int r = 0; r < 4; ++r) {
            float s1 = yacc[g][0][r] + yacc[g][1][r] + yacc[g][2][r] + yacc[g][3][r];
            float s2 = yacc[g][0][r] * yacc[g][0][r] + yacc[g][1][r] * yacc[g][1][r] +
                       yacc[g][2][r] * yacc[g][2][r] + yacc[g][3][r] * yacc[g][3][r];
#pragma unroll
            for (int o = 1; o <= 8; o <<= 1) {
                s1 += __shfl_xor(s1, o, 64);
                s2 += __shfl_xor(s2, o, 64);
            }
            float mu = s1 * (1.f / 64.f);
            float var = fmaxf(s2 * (1.f / 64.f) - mu * mu, 0.f);
            float rs = 1.f / sqrtf(var + 1e-5f);
            int nglob = n0 + wid * 32 + g * 16 + quad * 4 + r;
            size_t grow = (size_t)(b * 1024 + nglob);
#pragma unroll
            for (int dt = 0; dt < 4; ++dt) {
                int d = dt * 16 + l15;
                float yv = (yacc[g][dt][r] - mu) * rs;
                float gt = h2f(QKVGh[grow * 2048 + 1536 + h * 64 + d]);
                float sw = gt / (1.f + expf(-gt));
                Zh[grow * 512 + h * 64 + d] = f2h(yv * sw);
            }
        }
    }
}

// ---------- final FC ----------
__global__ __launch_bounds__(256) void fc_partial(const float* __restrict__ x3,
                                                  const float* __restrict__ fcW,
                                                  float* __restrict__ logits)
{
    __shared__ float red[4];
    int b = blockIdx.x >> 3, sl = blockIdx.x & 7;
    size_t xbase = (size_t)b * 524288 + (size_t)sl * 65536;
    size_t wbase = (size_t)sl * 65536;
    float s = 0.f;
    for (int i = threadIdx.x; i < 16384; i += 256) {
        float4 xv = *(const float4*)&x3[xbase + (size_t)i * 4];
        float4 wv = *(const float4*)&fcW[wbase + (size_t)i * 4];
        s += xv.x * wv.x + xv.y * wv.y + xv.z * wv.z + xv.w * wv.w;
    }
    int wid = threadIdx.x >> 6, lane = threadIdx.x & 63;
#pragma unroll
    for (int o = 32; o >= 1; o >>= 1) s += __shfl_xor(s, o, 64);
    if (lane == 0) red[wid] = s;
    __syncthreads();
    if (threadIdx.x == 0) atomicAdd(&logits[b], red[0] + red[1] + red[2] + red[3]);
}

__global__ void fc_final(const float* __restrict__ logits, const float* __restrict__ fcb,
                         float* __restrict__ out)
{
    int t = threadIdx.x;
    if (t < 8) {
        float l = logits[t] + fcb[0];
        out[t] = 1.f / (1.f + expf(-l));
    }
}

extern "C" void kernel_launch(void* const* d_in, const int* in_sizes, int n_in,
                              void* d_out, int out_size, void* d_ws, size_t ws_size,
                              hipStream_t stream)
{
    const int* ids = (const int*)d_in[0];
    const float* emb = (const float*)d_in[1];
    const float* pos = (const float*)d_in[2];
    const float* ln_g = (const float*)d_in[3];
    const float* ln_b = (const float*)d_in[4];
    const float* Wq = (const float*)d_in[5];
    const float* Wk = (const float*)d_in[6];
    const float* Wv = (const float*)d_in[7];
    const float* Wg = (const float*)d_in[8];
    const float* Wo = (const float*)d_in[9];
    const float* W1 = (const float*)d_in[10];
    const float* b1 = (const float*)d_in[11];
    const float* W2 = (const float*)d_in[12];
    const float* b2 = (const float*)d_in[13];
    const float* fcW = (const float*)d_in[14];
    const float* fcb = (const float*)d_in[15];
    float* out = (float*)d_out;

    char* ws = (char*)d_ws;
    u16* WT     = (u16*)(ws);                  //  3,670,016
    float* x0f  = (float*)(ws + 3670016);      // 16,777,216  LN(emb) f32 (residual)
    u16* x0h    = (u16*)(ws + 20447232);       //  8,388,608  LN(emb) f16
    u16* QKVGh  = (u16*)(ws + 28835840);       // 33,554,432  [8192][2048] f16
    float* X3   = (float*)(ws + 62390272);     // 16,777,216
    float* logits = (float*)(ws + 79167488);   // 32 B  (total ~79.2 MB < proven 99.6)
    u16* Zh   = x0h;                            // dead after QKVG GEMM
    float* X1 = (float*)QKVGh;                  // QKVGh dead after retention
    u16* Th   = (u16*)((char*)QKVGh + 16777216);
    u16* Hh   = (u16*)((char*)QKVGh + 25165824);
    float* X2 = x0f;                            // dead after Wo-GEMM residual

    // only vocab iteration i=2 is live (x overwritten each pass)
    transpose_w<<<dim3(8, 8, 7), 256, 0, stream>>>(Wq, Wk, Wv, Wg, Wo, W1, W2, WT);
    ln_kernel<<<8192, 256, 0, stream>>>(nullptr, ids, emb, pos, ln_g, ln_b, x0f, x0h, 1, nullptr);
    gemm_f16<<<dim3(16, 64), 256, 0, stream>>>(x0h, WT, nullptr, QKVGh, nullptr, nullptr, 4, 2048);
    retention_f16<<<512, 256, 0, stream>>>(QKVGh, Zh);
    gemm_f16<<<dim3(4, 64), 256, 0, stream>>>(Zh, WT + 4 * 262144, X1, nullptr, x0f, nullptr, 1, 512);
    ln_kernel<<<8192, 256, 0, stream>>>(X1, nullptr, nullptr, nullptr, ln_g, ln_b, nullptr, Th, 0, nullptr);
    gemm_f16<<<dim3(4, 64), 256, 0, stream>>>(Th, WT + 5 * 262144, nullptr, Hh, nullptr, b1, 2, 512);
    gemm_f16<<<dim3(4, 64), 256, 0, stream>>>(Hh, WT + 6 * 262144, X2, nullptr, X1, b2, 3, 512);
    ln_kernel<<<8192, 256, 0, stream>>>(X2, nullptr, nullptr, nullptr, ln_g, ln_b, X3, nullptr, 0, logits);
    fc_partial<<<64, 256, 0, stream>>>(X3, fcW, logits);
    fc_final<<<1, 64, 0, stream>>>(logits, fcb, out);
}